// Round 4
// baseline (259.333 us; speedup 1.0000x reference)
//
#include <hip/hip_runtime.h>
#include <hip/hip_bf16.h>

#define TPB 256

typedef float f2 __attribute__((ext_vector_type(2)));

// ws layout (fp32):
//   W[grp*256 + j*32 + k] = w1[j][grp*32 + k]   grp: 0 = u*m term, 1 = u term, 2 = m term
//   W[768 + j]  = b1[j]
//   W[776 + j]  = w2[j]
//   W[784]      = b2
// k-contiguous so the float2 pair {W[..][2d], W[..][2d+1]} is an aligned
// 8B load at a wave-uniform address -> s_load_dwordx2 (scalar pipe).

__global__ void prep_kernel(const float* __restrict__ w1,
                            const float* __restrict__ b1,
                            const float* __restrict__ w2,
                            const float* __restrict__ b2,
                            float* __restrict__ W) {
    int t = threadIdx.x;
    for (int i = t; i < 768; i += TPB) {
        int grp = i >> 8;        // which x-slice: u*m / u / m
        int r   = i & 255;
        int j   = r >> 5;        // hidden unit 0..7
        int k   = r & 31;        // factor 0..31
        W[i] = w1[j * 96 + grp * 32 + k];
    }
    if (t < 8) W[768 + t] = b1[t];
    if (t < 8) W[776 + t] = w2[t];
    if (t == 0) W[784]    = b2[0];
}

__global__ __launch_bounds__(TPB) void mf_kernel(
    const int* __restrict__ users, const int* __restrict__ movies,
    const float4* __restrict__ uemb,   // [1e6][8] x 16B (32 fp32/row)
    const float4* __restrict__ memb,   // [1e5][8]
    const float* __restrict__ W,
    float* __restrict__ out, int n) {
    int i = blockIdx.x * TPB + threadIdx.x;
    if (i >= n) return;

    int ui = users[i];
    int mi = movies[i];
    const float4* up = uemb + ((size_t)ui << 3);
    const float4* mp = memb + ((size_t)mi << 3);

    // Issue all 16 row loads up front (16 x global_load_dwordx4 in flight).
    float4 ua[8], ma[8];
#pragma unroll
    for (int q = 0; q < 8; ++q) ua[q] = up[q];
#pragma unroll
    for (int q = 0; q < 8; ++q) ma[q] = mp[q];

    const f2* Wp = (const f2*)W;   // pair index = grp*128 + j*16 + d

    // h2[j] = {sum over even k, sum over odd k}; bias seeds the .x half.
    f2 h2[8];
#pragma unroll
    for (int j = 0; j < 8; ++j) { h2[j].x = W[768 + j]; h2[j].y = 0.0f; }

#pragma unroll
    for (int q = 0; q < 8; ++q) {
        f2 u0, u1, m0, m1;
        u0.x = ua[q].x; u0.y = ua[q].y;  u1.x = ua[q].z; u1.y = ua[q].w;
        m0.x = ma[q].x; m0.y = ma[q].y;  m1.x = ma[q].z; m1.y = ma[q].w;
        f2 p0 = u0 * m0;                 // v_pk_mul_f32
        f2 p1 = u1 * m1;
        int d0 = 2 * q, d1 = 2 * q + 1;
#pragma unroll
        for (int j = 0; j < 8; ++j) {
            h2[j] = __builtin_elementwise_fma(p0, Wp[      j * 16 + d0], h2[j]);
            h2[j] = __builtin_elementwise_fma(u0, Wp[128 + j * 16 + d0], h2[j]);
            h2[j] = __builtin_elementwise_fma(m0, Wp[256 + j * 16 + d0], h2[j]);
            h2[j] = __builtin_elementwise_fma(p1, Wp[      j * 16 + d1], h2[j]);
            h2[j] = __builtin_elementwise_fma(u1, Wp[128 + j * 16 + d1], h2[j]);
            h2[j] = __builtin_elementwise_fma(m1, Wp[256 + j * 16 + d1], h2[j]);
        }
    }

    float z = W[784];
#pragma unroll
    for (int j = 0; j < 8; ++j) {
        float hj = h2[j].x + h2[j].y;
        z = fmaf(fmaxf(hj, 0.0f), W[776 + j], z);
    }

    out[i] = 1.0f / (1.0f + __expf(-z));
}

extern "C" void kernel_launch(void* const* d_in, const int* in_sizes, int n_in,
                              void* d_out, int out_size, void* d_ws, size_t ws_size,
                              hipStream_t stream) {
    const int* users   = (const int*)d_in[0];
    const int* movies  = (const int*)d_in[1];
    const float4* uemb = (const float4*)d_in[2];   // fp32 [1e6, 32]
    const float4* memb = (const float4*)d_in[3];   // fp32 [1e5, 32]
    const float* w1    = (const float*)d_in[4];    // fp32 [8, 96]
    const float* b1    = (const float*)d_in[5];    // fp32 [8]
    const float* w2    = (const float*)d_in[6];    // fp32 [1, 8]
    const float* b2    = (const float*)d_in[7];    // fp32 [1]
    float* ws = (float*)d_ws;
    float* out = (float*)d_out;

    int n = in_sizes[0];

    prep_kernel<<<1, TPB, 0, stream>>>(w1, b1, w2, b2, ws);
    mf_kernel<<<(n + TPB - 1) / TPB, TPB, 0, stream>>>(users, movies, uemb, memb, ws, out, n);
}